// Round 1
// baseline (243.245 us; speedup 1.0000x reference)
//
#include <hip/hip_runtime.h>
#include <hip/hip_bf16.h>

// Reference collapses: softmax over a size-1 key axis == 1.0, so
// out[bn,t,:] = padded[bn,t,:] + (masked_mean_t(padded[bn]) @ Wv + bv).
// q/k/rope/positions/sum_token are dead code.

#define DM 384
#define TT 128

__global__ __launch_bounds__(DM) void gmha_collapsed_kernel(
    const float* __restrict__ padded,   // (BN, T, D)
    const float* __restrict__ Wv,       // (D, D) row-major: Wv[e*D + d]
    const float* __restrict__ bv,       // (D,)
    const int*   __restrict__ masks,    // (BN, T)
    float*       __restrict__ out)      // (BN, T, D)
{
    const int bn = blockIdx.x;
    const int d  = threadIdx.x;          // 0..383, one output column per thread

    __shared__ float w_sh[TT];
    __shared__ float summ_sh[DM];

    const float* __restrict__ p = padded + (size_t)bn * TT * DM;
    float*       __restrict__ o = out    + (size_t)bn * TT * DM;

    // stage mask weights
    if (d < TT) w_sh[d] = (float)masks[bn * TT + d];
    __syncthreads();

    // denom (every thread computes it redundantly from LDS broadcast reads)
    float wsum = 0.f;
    #pragma unroll
    for (int t = 0; t < TT; ++t) wsum += w_sh[t];
    const float denom = fmaxf(wsum, 1e-6f);

    // masked column sum over T (coalesced: lane d reads consecutive addresses)
    float s = 0.f;
    #pragma unroll 8
    for (int t = 0; t < TT; ++t) {
        s += p[(size_t)t * DM + d] * w_sh[t];
    }
    const float summ = s / denom;
    summ_sh[d] = summ;
    __syncthreads();

    // matvec: v[d] = bv[d] + sum_e summary[e] * Wv[e][d]
    // summ_sh[e] is wave-uniform (broadcast, conflict-free); Wv read coalesced.
    float acc = bv[d];
    #pragma unroll 8
    for (int e = 0; e < DM; ++e) {
        acc += summ_sh[e] * Wv[(size_t)e * DM + d];
    }

    // out = padded + v (tile re-read hits L2/L3)
    #pragma unroll 8
    for (int t = 0; t < TT; ++t) {
        o[(size_t)t * DM + d] = p[(size_t)t * DM + d] + acc;
    }
}

extern "C" void kernel_launch(void* const* d_in, const int* in_sizes, int n_in,
                              void* d_out, int out_size, void* d_ws, size_t ws_size,
                              hipStream_t stream) {
    const float* padded = (const float*)d_in[0];
    // d_in[1] sum_token   : unused by reference
    // d_in[2] positions_3d: dead code (softmax over size-1 axis)
    // d_in[3] Wq, d_in[4] bq, d_in[5] Wk, d_in[6] bk: dead code
    const float* Wv     = (const float*)d_in[7];
    const float* bv     = (const float*)d_in[8];
    const int*   masks  = (const int*)d_in[9];
    float* out = (float*)d_out;

    const int BN = 8 * 64;  // B*N = 512 blocks
    gmha_collapsed_kernel<<<BN, DM, 0, stream>>>(padded, Wv, bv, masks, out);
}

// Round 2
// 228.574 us; speedup vs baseline: 1.0642x; 1.0642x over previous
//
#include <hip/hip_runtime.h>
#include <hip/hip_bf16.h>

// Reference collapses: softmax over a size-1 key axis == 1.0, so
// out[bn,t,:] = padded[bn,t,:] + (masked_mean_t(padded[bn]) @ Wv + bv).
// q/k/rope/positions/sum_token are dead code.
//
// R2: full float4 vectorization. Thread layout: c = t%96 (float4 column),
// r = t/96 (0..3, row-group / e-range). Phase1 and matvec each do a 4-way
// LDS partial reduce. Per-thread memory instrs: 32+96+64 dwordx4 (was 768
// scalar dword in R1 -> latency-bound at 1.9 TB/s).

#define DM 384
#define TT 128
#define C4 96   // DM / 4

__global__ __launch_bounds__(384) void gmha_v2_kernel(
    const float* __restrict__ padded,   // (BN, T, D)
    const float* __restrict__ Wv,       // (D, D) row-major
    const float* __restrict__ bv,       // (D,)
    const int*   __restrict__ masks,    // (BN, T)
    float*       __restrict__ out)      // (BN, T, D)
{
    const int bn = blockIdx.x;
    const int t  = threadIdx.x;
    const int c  = t % C4;      // float4 column 0..95
    const int r  = t / C4;      // 0..3

    __shared__ float  w_sh[TT];
    __shared__ float4 part_sh[4][C4];
    __shared__ float  summ_sh[DM];
    __shared__ float4 v_sh[C4];

    const float4* __restrict__ p4 = (const float4*)(padded + (size_t)bn * TT * DM);
    float4*       __restrict__ o4 = (float4*)(out    + (size_t)bn * TT * DM);

    if (t < TT) w_sh[t] = (float)masks[bn * TT + t];
    __syncthreads();

    // denom — redundant per thread, LDS broadcast reads are cheap
    float wsum = 0.f;
    #pragma unroll
    for (int i = 0; i < TT; ++i) wsum += w_sh[i];
    const float inv_denom = 1.0f / fmaxf(wsum, 1e-6f);

    // phase 1: partial masked column sums over rows r, r+4, ...
    float4 acc = make_float4(0.f, 0.f, 0.f, 0.f);
    #pragma unroll 8
    for (int tt = r; tt < TT; tt += 4) {
        const float  w = w_sh[tt];
        const float4 x = p4[tt * C4 + c];
        acc.x += x.x * w; acc.y += x.y * w; acc.z += x.z * w; acc.w += x.w * w;
    }
    part_sh[r][c] = acc;
    __syncthreads();

    if (t < C4) {
        const float4 a0 = part_sh[0][t], a1 = part_sh[1][t];
        const float4 a2 = part_sh[2][t], a3 = part_sh[3][t];
        float4 s;
        s.x = (a0.x + a1.x + a2.x + a3.x) * inv_denom;
        s.y = (a0.y + a1.y + a2.y + a3.y) * inv_denom;
        s.z = (a0.z + a1.z + a2.z + a3.z) * inv_denom;
        s.w = (a0.w + a1.w + a2.w + a3.w) * inv_denom;
        ((float4*)summ_sh)[t] = s;
    }
    __syncthreads();

    // phase 2: matvec v = summary @ Wv + bv, split e-range across r
    float4 vacc = make_float4(0.f, 0.f, 0.f, 0.f);
    const int e0 = r * 96;
    #pragma unroll 8
    for (int i = 0; i < 96; ++i) {
        const int   e  = e0 + i;
        const float se = summ_sh[e];
        const float4 wv = *(const float4*)(Wv + (size_t)e * DM + 4 * c);
        vacc.x += se * wv.x; vacc.y += se * wv.y;
        vacc.z += se * wv.z; vacc.w += se * wv.w;
    }
    part_sh[r][c] = vacc;
    __syncthreads();

    if (t < C4) {
        const float4 a0 = part_sh[0][t], a1 = part_sh[1][t];
        const float4 a2 = part_sh[2][t], a3 = part_sh[3][t];
        const float4 b  = ((const float4*)bv)[t];
        float4 v;
        v.x = a0.x + a1.x + a2.x + a3.x + b.x;
        v.y = a0.y + a1.y + a2.y + a3.y + b.y;
        v.z = a0.z + a1.z + a2.z + a3.z + b.z;
        v.w = a0.w + a1.w + a2.w + a3.w + b.w;
        v_sh[t] = v;
    }
    __syncthreads();

    // phase 3: out = padded + v (tile re-read hits L2/L3)
    const float4 v = v_sh[c];
    #pragma unroll 8
    for (int tt = r; tt < TT; tt += 4) {
        float4 x = p4[tt * C4 + c];
        x.x += v.x; x.y += v.y; x.z += v.z; x.w += v.w;
        o4[tt * C4 + c] = x;
    }
}

extern "C" void kernel_launch(void* const* d_in, const int* in_sizes, int n_in,
                              void* d_out, int out_size, void* d_ws, size_t ws_size,
                              hipStream_t stream) {
    const float* padded = (const float*)d_in[0];
    // d_in[1] sum_token, d_in[2] positions_3d, d_in[3..6] Wq/bq/Wk/bk: dead code
    const float* Wv     = (const float*)d_in[7];
    const float* bv     = (const float*)d_in[8];
    const int*   masks  = (const int*)d_in[9];
    float* out = (float*)d_out;

    const int BN = 8 * 64;  // 512 blocks, one per (b,n)
    gmha_v2_kernel<<<BN, 384, 0, stream>>>(padded, Wv, bv, masks, out);
}

// Round 3
// 223.789 us; speedup vs baseline: 1.0869x; 1.0214x over previous
//
#include <hip/hip_runtime.h>
#include <hip/hip_bf16.h>

// Reference collapses: softmax over a size-1 key axis == 1.0, so
// out[bn,t,:] = padded[bn,t,:] + (masked_mean_t(padded[bn]) @ Wv + bv).
// q/k/rope/positions/sum_token are dead code.
//
// R3: 768 threads/block (12 waves). 512 blocks -> 2 blocks/CU -> 24 waves/CU
// (75% occupancy ceiling vs R2's 37.5%). Thread: c = t%96 (float4 col),
// r = t/96 (0..7). Phase1: 16 unrolled dwordx4 loads/thread. Phase2: e-range
// split 8-way (Wv read exactly once per block). Phase3: 16 load+add+store.

#define DM 384
#define TT 128
#define C4 96          // DM / 4
#define RG 8           // row groups
#define NT (C4 * RG)   // 768 threads = 12 waves

__global__ __launch_bounds__(NT) void gmha_v3_kernel(
    const float* __restrict__ padded,   // (BN, T, D)
    const float* __restrict__ Wv,       // (D, D) row-major
    const float* __restrict__ bv,       // (D,)
    const int*   __restrict__ masks,    // (BN, T)
    float*       __restrict__ out)      // (BN, T, D)
{
    const int bn = blockIdx.x;
    const int t  = threadIdx.x;
    const int c  = t % C4;      // float4 column 0..95
    const int r  = t / C4;      // 0..7

    __shared__ float  w_sh[TT];
    __shared__ float4 part_sh[RG][C4];
    __shared__ float  summ_sh[DM];
    __shared__ float4 v_sh[C4];

    const float4* __restrict__ p4 = (const float4*)(padded + (size_t)bn * TT * DM);
    float4*       __restrict__ o4 = (float4*)(out    + (size_t)bn * TT * DM);

    if (t < TT) w_sh[t] = (float)masks[bn * TT + t];
    __syncthreads();

    // phase 1: masked partial column sums; thread covers rows r, r+8, ... (16 rows)
    float4 acc = make_float4(0.f, 0.f, 0.f, 0.f);
    #pragma unroll
    for (int i = 0; i < TT / RG; ++i) {
        const int    tt = r + i * RG;
        const float  w  = w_sh[tt];
        const float4 x  = p4[tt * C4 + c];
        acc.x += x.x * w; acc.y += x.y * w; acc.z += x.z * w; acc.w += x.w * w;
    }
    part_sh[r][c] = acc;
    __syncthreads();

    if (t < C4) {
        float wsum = 0.f;
        #pragma unroll
        for (int i = 0; i < TT; ++i) wsum += w_sh[i];
        const float inv_denom = 1.0f / fmaxf(wsum, 1e-6f);
        float4 s = make_float4(0.f, 0.f, 0.f, 0.f);
        #pragma unroll
        for (int g = 0; g < RG; ++g) {
            const float4 a = part_sh[g][t];
            s.x += a.x; s.y += a.y; s.z += a.z; s.w += a.w;
        }
        s.x *= inv_denom; s.y *= inv_denom; s.z *= inv_denom; s.w *= inv_denom;
        ((float4*)summ_sh)[t] = s;
    }
    __syncthreads();

    // phase 2: matvec v = summary @ Wv + bv; r handles e in [r*48, r*48+48)
    float4 vacc = make_float4(0.f, 0.f, 0.f, 0.f);
    const int e0 = r * (DM / RG);
    #pragma unroll 8
    for (int i = 0; i < DM / RG; ++i) {
        const int   e  = e0 + i;
        const float se = summ_sh[e];
        const float4 wv = *(const float4*)(Wv + (size_t)e * DM + 4 * c);
        vacc.x += se * wv.x; vacc.y += se * wv.y;
        vacc.z += se * wv.z; vacc.w += se * wv.w;
    }
    part_sh[r][c] = vacc;
    __syncthreads();

    if (t < C4) {
        float4 v = ((const float4*)bv)[t];
        #pragma unroll
        for (int g = 0; g < RG; ++g) {
            const float4 a = part_sh[g][t];
            v.x += a.x; v.y += a.y; v.z += a.z; v.w += a.w;
        }
        v_sh[t] = v;
    }
    __syncthreads();

    // phase 3: out = padded + v (tile re-read hits L2/L3)
    const float4 v = v_sh[c];
    #pragma unroll
    for (int i = 0; i < TT / RG; ++i) {
        const int tt = r + i * RG;
        float4 x = p4[tt * C4 + c];
        x.x += v.x; x.y += v.y; x.z += v.z; x.w += v.w;
        o4[tt * C4 + c] = x;
    }
}

extern "C" void kernel_launch(void* const* d_in, const int* in_sizes, int n_in,
                              void* d_out, int out_size, void* d_ws, size_t ws_size,
                              hipStream_t stream) {
    const float* padded = (const float*)d_in[0];
    // d_in[1] sum_token, d_in[2] positions_3d, d_in[3..6] Wq/bq/Wk/bk: dead code
    const float* Wv     = (const float*)d_in[7];
    const float* bv     = (const float*)d_in[8];
    const int*   masks  = (const int*)d_in[9];
    float* out = (float*)d_out;

    const int BN = 8 * 64;  // 512 blocks, one per (b,n)
    gmha_v3_kernel<<<BN, NT, 0, stream>>>(padded, Wv, bv, masks, out);
}

// Round 4
// 222.325 us; speedup vs baseline: 1.0941x; 1.0066x over previous
//
#include <hip/hip_runtime.h>
#include <hip/hip_bf16.h>

// Reference collapses: softmax over a size-1 key axis == 1.0, so
// out[bn,t,:] = padded[bn,t,:] + (masked_mean_t(padded[bn]) @ Wv + bv).
// q/k/rope/positions/sum_token are dead code.
//
// R4: 3-kernel split so every phase is massively parallel and individually
// BW-saturating (R3's fused version serialized phases behind per-block
// barriers at 2 blocks/CU -> 2.5 TB/s only).
//   K1: masked partial column sums  (1024 blocks, pure 100 MB read)
//   K2: finalize summary + matvec   (256 blocks, 2 bn each, Wv from L2)
//   K3: out = padded + v            (2048 blocks, pure streaming)
// ws layout: [0 .. 1024*384)   float partials (bn,half,col)
//            [1024*384 .. +512*384) float v

#define DM 384
#define TT 128
#define C4 96          // DM / 4
#define BN_TOT 512

// ---------------- K1: partial masked column sums ----------------
// block b: bn = b>>1, half = b&1 (rows half*64 .. half*64+63)
// 384 threads: c = t%96 (float4 col), r = t/96 (0..3); 16 rows/thread.
__global__ __launch_bounds__(384) void k1_partial_sums(
    const float* __restrict__ padded,
    const int*   __restrict__ masks,
    float*       __restrict__ ws_part)   // (BN, 2, DM)
{
    const int bn   = blockIdx.x >> 1;
    const int half = blockIdx.x & 1;
    const int t = threadIdx.x;
    const int c = t % C4;
    const int r = t / C4;            // 0..3

    __shared__ float  w_sh[64];
    __shared__ float4 part_sh[4][C4];

    if (t < 64) w_sh[t] = (float)masks[bn * TT + half * 64 + t];
    __syncthreads();

    const float4* __restrict__ p4 =
        (const float4*)(padded + (size_t)bn * TT * DM) + half * 64 * C4;

    float4 acc = make_float4(0.f, 0.f, 0.f, 0.f);
    #pragma unroll
    for (int i = 0; i < 16; ++i) {
        const int    tt = r + i * 4;          // 0..63 within half
        const float  w  = w_sh[tt];
        const float4 x  = p4[tt * C4 + c];
        acc.x += x.x * w; acc.y += x.y * w; acc.z += x.z * w; acc.w += x.w * w;
    }
    part_sh[r][c] = acc;
    __syncthreads();

    if (t < C4) {
        const float4 a0 = part_sh[0][t], a1 = part_sh[1][t];
        const float4 a2 = part_sh[2][t], a3 = part_sh[3][t];
        float4 s;
        s.x = a0.x + a1.x + a2.x + a3.x;
        s.y = a0.y + a1.y + a2.y + a3.y;
        s.z = a0.z + a1.z + a2.z + a3.z;
        s.w = a0.w + a1.w + a2.w + a3.w;
        ((float4*)(ws_part + ((size_t)bn * 2 + half) * DM))[t] = s;
    }
}

// ---------------- K2: finalize summary + matvec ----------------
// block handles bn0 = 2*blockIdx, bn1 = bn0+1. 384 threads.
__global__ __launch_bounds__(384) void k2_matvec(
    const float* __restrict__ ws_part,   // (BN, 2, DM)
    const int*   __restrict__ masks,
    const float* __restrict__ Wv,
    const float* __restrict__ bv,
    float*       __restrict__ ws_v)      // (BN, DM)
{
    const int bn0 = blockIdx.x * 2;
    const int bn1 = bn0 + 1;
    const int t = threadIdx.x;
    const int c = t % C4;
    const int r = t / C4;            // 0..3

    __shared__ float summ0[DM], summ1[DM];
    __shared__ float4 part0[4][C4], part1[4][C4];
    __shared__ float w0_sh[TT], w1_sh[TT];

    if (t < TT) w0_sh[t] = (float)masks[bn0 * TT + t];
    else if (t < 2 * TT) w1_sh[t - TT] = (float)masks[bn1 * TT + (t - TT)];
    __syncthreads();

    if (t < C4) {
        float ws0 = 0.f, ws1 = 0.f;
        #pragma unroll
        for (int i = 0; i < TT; ++i) { ws0 += w0_sh[i]; ws1 += w1_sh[i]; }
        const float id0 = 1.0f / fmaxf(ws0, 1e-6f);
        const float id1 = 1.0f / fmaxf(ws1, 1e-6f);
        const float4 p00 = ((const float4*)(ws_part + (size_t)bn0 * 2 * DM))[t];
        const float4 p01 = ((const float4*)(ws_part + ((size_t)bn0 * 2 + 1) * DM))[t];
        const float4 p10 = ((const float4*)(ws_part + (size_t)bn1 * 2 * DM))[t];
        const float4 p11 = ((const float4*)(ws_part + ((size_t)bn1 * 2 + 1) * DM))[t];
        float4 s0, s1;
        s0.x = (p00.x + p01.x) * id0; s0.y = (p00.y + p01.y) * id0;
        s0.z = (p00.z + p01.z) * id0; s0.w = (p00.w + p01.w) * id0;
        s1.x = (p10.x + p11.x) * id1; s1.y = (p10.y + p11.y) * id1;
        s1.z = (p10.z + p11.z) * id1; s1.w = (p10.w + p11.w) * id1;
        ((float4*)summ0)[t] = s0;
        ((float4*)summ1)[t] = s1;
    }
    __syncthreads();

    // matvec for both bn; Wv float4 loaded once, used twice
    float4 a0 = make_float4(0.f, 0.f, 0.f, 0.f);
    float4 a1 = make_float4(0.f, 0.f, 0.f, 0.f);
    const int e0 = r * C4;
    #pragma unroll 8
    for (int i = 0; i < C4; ++i) {
        const int   e  = e0 + i;
        const float s0 = summ0[e];
        const float s1 = summ1[e];
        const float4 wv = *(const float4*)(Wv + (size_t)e * DM + 4 * c);
        a0.x += s0 * wv.x; a0.y += s0 * wv.y; a0.z += s0 * wv.z; a0.w += s0 * wv.w;
        a1.x += s1 * wv.x; a1.y += s1 * wv.y; a1.z += s1 * wv.z; a1.w += s1 * wv.w;
    }
    part0[r][c] = a0;
    part1[r][c] = a1;
    __syncthreads();

    if (t < C4) {
        const float4 b = ((const float4*)bv)[t];
        float4 v0 = b, v1 = b;
        #pragma unroll
        for (int g = 0; g < 4; ++g) {
            const float4 q0 = part0[g][t], q1 = part1[g][t];
            v0.x += q0.x; v0.y += q0.y; v0.z += q0.z; v0.w += q0.w;
            v1.x += q1.x; v1.y += q1.y; v1.z += q1.z; v1.w += q1.w;
        }
        ((float4*)(ws_v + (size_t)bn0 * DM))[t] = v0;
        ((float4*)(ws_v + (size_t)bn1 * DM))[t] = v1;
    }
}

// ---------------- K3: out = padded + v ----------------
// block b: bn = b>>2, quarter q = b&3 (rows q*32 .. q*32+31). 384 threads.
__global__ __launch_bounds__(384) void k3_add(
    const float* __restrict__ padded,
    const float* __restrict__ ws_v,
    float*       __restrict__ out)
{
    const int bn = blockIdx.x >> 2;
    const int q  = blockIdx.x & 3;
    const int t = threadIdx.x;
    const int c = t % C4;
    const int r = t / C4;            // 0..3

    __shared__ float4 v_sh[C4];
    if (t < C4) v_sh[t] = ((const float4*)(ws_v + (size_t)bn * DM))[t];
    __syncthreads();

    const size_t base = (size_t)bn * TT * C4 + (size_t)q * 32 * C4;
    const float4* __restrict__ p4 = (const float4*)padded + base;
    float4*       __restrict__ o4 = (float4*)out + base;

    const float4 v = v_sh[c];
    #pragma unroll
    for (int i = 0; i < 8; ++i) {
        const int tt = r + i * 4;     // 0..31 within quarter
        float4 x = p4[tt * C4 + c];
        x.x += v.x; x.y += v.y; x.z += v.z; x.w += v.w;
        o4[tt * C4 + c] = x;
    }
}

extern "C" void kernel_launch(void* const* d_in, const int* in_sizes, int n_in,
                              void* d_out, int out_size, void* d_ws, size_t ws_size,
                              hipStream_t stream) {
    const float* padded = (const float*)d_in[0];
    // d_in[1] sum_token, d_in[2] positions_3d, d_in[3..6] Wq/bq/Wk/bk: dead code
    const float* Wv     = (const float*)d_in[7];
    const float* bv     = (const float*)d_in[8];
    const int*   masks  = (const int*)d_in[9];
    float* out = (float*)d_out;

    float* ws_part = (float*)d_ws;                       // 1024*384 floats
    float* ws_v    = ws_part + (size_t)BN_TOT * 2 * DM;  // 512*384 floats

    k1_partial_sums<<<BN_TOT * 2, 384, 0, stream>>>(padded, masks, ws_part);
    k2_matvec<<<BN_TOT / 2, 384, 0, stream>>>(ws_part, masks, Wv, bv, ws_v);
    k3_add<<<BN_TOT * 4, 384, 0, stream>>>(padded, ws_v, out);
}